// Round 2
// baseline (89.575 us; speedup 1.0000x reference)
//
#include <hip/hip_runtime.h>
#include <hip/hip_bf16.h>

typedef short v8s __attribute__((ext_vector_type(8)));
typedef float v16f __attribute__((ext_vector_type(16)));

// float -> bf16 bits (RNE)
__device__ __forceinline__ short f2bf(float f) {
    unsigned u = __builtin_bit_cast(unsigned, f);
    u = u + 0x7FFFu + ((u >> 16) & 1u);
    return (short)(u >> 16);
}

// ---------------------------------------------------------------------------
// Prep: U3/U2 -> fragment-ordered bf16 B matrix in global workspace.
// Layout: Bg[kt(12)][nt(8)][lane(64)][j(8)]  (shorts), kt stride 4096 shorts.
//   B[k3*16+i, n=p*16+q] = U3[p,q,i,k3]  (kt=k3<11, lane = (n&31)|((i>>3)<<5), j=i&7)
//   kt=11: B[176+k2, n] = U2[p,q,k2] at j=k2<4, rest zero.
// ---------------------------------------------------------------------------
__global__ void symcon_prep(const float* __restrict__ U3, const float* __restrict__ U2,
                            short* __restrict__ Bg)
{
    const int g = blockIdx.x * 256 + threadIdx.x;   // 0..4095
    const int n = g >> 4;                           // output column 0..255
    const int i = g & 15;                           // irrep index 0..15
    const int nt = n >> 5;
    const int lb = n & 31;
    const int lane = lb | ((i >> 3) << 5);
    const int j = i & 7;
    const float* u3p = U3 + n * 176 + i * 11;       // U3[n, i, k3] contiguous in k3
    short* dst = Bg + ((nt * 64 + lane) << 3) + j;  // kt=0 slot
    #pragma unroll
    for (int k3 = 0; k3 < 11; ++k3)
        dst[k3 * 4096] = f2bf(u3p[k3]);
    if (i == 0) {
        // kt = 11 block: U2 in k=0..3 of the low half, everything else zero
        short* d0 = Bg + 11 * 4096 + ((nt * 64 + lb) << 3);
        const float* u2p = U2 + n * 4;
        #pragma unroll
        for (int jj = 0; jj < 4; ++jj) d0[jj] = f2bf(u2p[jj]);
        #pragma unroll
        for (int jj = 4; jj < 8; ++jj) d0[jj] = 0;
        short* d1 = Bg + 11 * 4096 + ((nt * 64 + lb + 32) << 3);
        #pragma unroll
        for (int jj = 0; jj < 8; ++jj) d1[jj] = 0;
    }
}

// ---------------------------------------------------------------------------
// Main: one node (128 rows) per block. 4 waves in 2M x 2N arrangement.
//   A[m, k3*16+i] = x[m,i]*w3[m,k3] (built on the fly); B from global (L2).
// final[m] = sum_n D[m,n]*x[m,p]*x[m,q] + w1[m]*(U1 . x[m])
// ---------------------------------------------------------------------------
__global__ __launch_bounds__(256, 3)
void symcon_main(const float* __restrict__ x, const float* __restrict__ y,
                 const float* __restrict__ U1, const float* __restrict__ W3,
                 const float* __restrict__ W2, const float* __restrict__ W1,
                 const short* __restrict__ Bg, float* __restrict__ out)
{
    __shared__ __align__(16) float x_re[128][16];   // permuted x tile (8 KB)
    __shared__ __align__(16) float Sbuf[128][68];   // cross-wave reduce (34 KB)

    const int tid  = threadIdx.x;
    const int tile = blockIdx.x;

    // ---- stage permuted x tile: x_re[r][(i&1)*8 + (i>>1)] = x[r][i] ----
    {
        const int r = tid >> 1, hf = tid & 1;
        const float* xp = x + ((size_t)tile * 128 + r) * 16 + hf * 8;
        const float4 a = *reinterpret_cast<const float4*>(xp);
        const float4 b = *reinterpret_cast<const float4*>(xp + 4);
        const float4 ev = make_float4(a.x, a.z, b.x, b.z);   // even i
        const float4 od = make_float4(a.y, a.w, b.y, b.w);   // odd  i
        *reinterpret_cast<float4*>(&x_re[r][hf * 4])     = ev;
        *reinterpret_cast<float4*>(&x_re[r][8 + hf * 4]) = od;
    }

    // ---- species (argmax, first-max wins) ----
    int e = 0;
    {
        const float* yr = y + tile * 10;
        float best = yr[0];
        #pragma unroll
        for (int s2 = 1; s2 < 10; ++s2) { const float v = yr[s2]; if (v > best) { best = v; e = s2; } }
    }

    const int lane = tid & 63;
    const int wid  = tid >> 6;
    const int mw   = wid >> 1;      // M half of block tile
    const int nw   = wid & 1;       // N half
    const int col  = lane & 31;
    const int h    = lane >> 5;

    const int r0 = mw * 64 + col;   // local row, mr=0
    const int r1 = r0 + 32;         // local row, mr=1

    // ---- per-lane weights (channel c == local row) ----
    float w3a[11], w3b[11], w2a[4], w2b[4];
    #pragma unroll
    for (int k = 0; k < 11; ++k) {
        w3a[k] = W3[(e * 11 + k) * 128 + r0];
        w3b[k] = W3[(e * 11 + k) * 128 + r1];
    }
    #pragma unroll
    for (int k = 0; k < 4; ++k) {
        w2a[k] = W2[(e * 4 + k) * 128 + r0];
        w2b[k] = W2[(e * 4 + k) * 128 + r1];
    }

    // U1 in x_re slot order
    float u1p[16];
    #pragma unroll
    for (int s = 0; s < 16; ++s) {
        const int s2 = (s < 8) ? s : (s - 8);
        const int i  = ((s2 >> 2) << 3) + ((s2 & 3) << 1) + ((s < 8) ? 0 : 1);
        u1p[s] = U1[i];
    }

    __syncthreads();   // x_re ready

    // xsel quads: x[row][h*8 + j]  (even j / odd j)
    float xe0[4], xo0[4], xe1[4], xo1[4];
    {
        const float4 a = *reinterpret_cast<float4*>(&x_re[r0][h * 4]);
        const float4 b = *reinterpret_cast<float4*>(&x_re[r0][8 + h * 4]);
        const float4 c = *reinterpret_cast<float4*>(&x_re[r1][h * 4]);
        const float4 d = *reinterpret_cast<float4*>(&x_re[r1][8 + h * 4]);
        xe0[0]=a.x; xe0[1]=a.y; xe0[2]=a.z; xe0[3]=a.w;
        xo0[0]=b.x; xo0[1]=b.y; xo0[2]=b.z; xo0[3]=b.w;
        xe1[0]=c.x; xe1[1]=c.y; xe1[2]=c.z; xe1[3]=c.w;
        xo1[0]=d.x; xo1[1]=d.y; xo1[2]=d.z; xo1[3]=d.w;
    }

    v16f acc[8] = {};   // [mr*4 + ntl]

    // ---- K loop: 11 U3 steps + 1 U2 step; B fragments straight from L2 ----
    #pragma unroll
    for (int kt = 0; kt < 12; ++kt) {
        v8s bf[4];
        #pragma unroll
        for (int ntl = 0; ntl < 4; ++ntl) {
            const int ntg = nw * 4 + ntl;
            bf[ntl] = *reinterpret_cast<const v8s*>(&Bg[((kt * 8 + ntg) * 64 + lane) << 3]);
        }
        v8s a0, a1;
        if (kt < 11) {
            const float wa = w3a[kt], wb = w3b[kt];
            #pragma unroll
            for (int j = 0; j < 8; ++j) {
                const float xs0 = (j & 1) ? xo0[j >> 1] : xe0[j >> 1];
                const float xs1 = (j & 1) ? xo1[j >> 1] : xe1[j >> 1];
                a0[j] = f2bf(xs0 * wa);
                a1[j] = f2bf(xs1 * wb);
            }
        } else {
            #pragma unroll
            for (int j = 0; j < 8; ++j) {
                const float f0 = (j < 4 && h == 0) ? w2a[j & 3] : 0.f;
                const float f1 = (j < 4 && h == 0) ? w2b[j & 3] : 0.f;
                a0[j] = f2bf(f0);
                a1[j] = f2bf(f1);
            }
        }
        #pragma unroll
        for (int ntl = 0; ntl < 4; ++ntl) {
            acc[ntl]     = __builtin_amdgcn_mfma_f32_32x32x16_bf16(a0, bf[ntl], acc[ntl],     0, 0, 0);
            acc[4 + ntl] = __builtin_amdgcn_mfma_f32_32x32x16_bf16(a1, bf[ntl], acc[4 + ntl], 0, 0, 0);
        }
    }

    // ---- epilogue: S[m] partial = sum_n D[m,n]*x[m,p]*x[m,q] (this wave's n-half) ----
    const int q     = col & 15;
    const int qslot = ((q & 1) << 3) | (q >> 1);
    const int c4    = col >> 4;
    #pragma unroll
    for (int mr = 0; mr < 2; ++mr) {
        const int rb = mw * 64 + mr * 32 + 4 * h;
        #pragma unroll
        for (int rg = 0; rg < 16; ++rg) {
            const int row = rb + (rg & 3) + ((rg >> 2) << 3);
            const float  xq  = x_re[row][qslot];
            const float4 xp4 = *reinterpret_cast<float4*>(&x_re[row][c4 * 8 + nw * 4]);
            float s  = acc[mr * 4 + 0][rg] * xp4.x;
            s += acc[mr * 4 + 1][rg] * xp4.y;
            s += acc[mr * 4 + 2][rg] * xp4.z;
            s += acc[mr * 4 + 3][rg] * xp4.w;
            Sbuf[row][nw * 32 + col] = s * xq;
        }
    }

    // U1 term (reads x_re BEFORE the barrier)
    const int myrow = mw * 64 + lane;
    float u1dot = 0.f;
    #pragma unroll
    for (int s4 = 0; s4 < 4; ++s4) {
        const float4 xv = *reinterpret_cast<float4*>(&x_re[myrow][s4 * 4]);
        u1dot += xv.x * u1p[s4*4+0] + xv.y * u1p[s4*4+1] + xv.z * u1p[s4*4+2] + xv.w * u1p[s4*4+3];
    }
    const float w1v = W1[e * 128 + myrow];
    __syncthreads();   // Sbuf complete

    if (nw == 0) {
        float tot = u1dot * w1v;
        #pragma unroll
        for (int cc = 0; cc < 16; ++cc) {
            const float4 sv = *reinterpret_cast<float4*>(&Sbuf[myrow][cc * 4]);
            tot += sv.x + sv.y + sv.z + sv.w;
        }
        out[(size_t)tile * 128 + myrow] = tot;
    }
}

extern "C" void kernel_launch(void* const* d_in, const int* in_sizes, int n_in,
                              void* d_out, int out_size, void* d_ws, size_t ws_size,
                              hipStream_t stream) {
    const float* x  = (const float*)d_in[0];
    const float* y  = (const float*)d_in[1];
    const float* U3 = (const float*)d_in[2];
    const float* U2 = (const float*)d_in[3];
    const float* U1 = (const float*)d_in[4];
    const float* W3 = (const float*)d_in[5];
    const float* W2 = (const float*)d_in[6];
    const float* W1 = (const float*)d_in[7];
    short* Bg = (short*)d_ws;   // 12*8*64*8 shorts = 96 KB, fits standard scratch

    symcon_prep<<<16, 256, 0, stream>>>(U3, U2, Bg);
    symcon_main<<<2048, 256, 0, stream>>>(x, y, U1, W3, W2, W1, Bg, (float*)d_out);
}

// Round 3
// 53.773 us; speedup vs baseline: 1.6658x; 1.6658x over previous
//
#include <hip/hip_runtime.h>
#include <hip/hip_bf16.h>

typedef short v8s __attribute__((ext_vector_type(8)));
typedef float v16f __attribute__((ext_vector_type(16)));

__device__ __forceinline__ short bfbits(float f) {
    return __builtin_bit_cast(short, __float2bfloat16(f));
}

// ---------------------------------------------------------------------------
// Prep: U3/U2 -> fragment-ordered bf16 B matrix in global workspace.
// Layout: Bg[kt(12)][nt(8)][lane(64)][j(8)] shorts; kt stride 4096.
//   B[k3*16+i, n=p*16+q] = U3[p,q,i,k3]  (lane=(n&31)|((i>>3)<<5), j=i&7)
//   kt=11: B[176+k2, n] = U2[n,k2] at h=0,j=k2<4; rest zero.
// ---------------------------------------------------------------------------
__global__ void symcon_prep(const float* __restrict__ U3, const float* __restrict__ U2,
                            short* __restrict__ Bg)
{
    const int g = blockIdx.x * 256 + threadIdx.x;   // 0..4095
    const int n = g >> 4;                           // output column 0..255
    const int i = g & 15;                           // irrep index 0..15
    const int nt = n >> 5;
    const int lb = n & 31;
    const int lane = lb | ((i >> 3) << 5);
    const int j = i & 7;
    const float* u3p = U3 + n * 176 + i * 11;       // U3[n,i,k3] contiguous in k3
    short* dst = Bg + ((nt * 64 + lane) << 3) + j;
    #pragma unroll
    for (int k3 = 0; k3 < 11; ++k3)
        dst[k3 * 4096] = bfbits(u3p[k3]);
    if (i == 0) {
        short* d0 = Bg + 11 * 4096 + ((nt * 64 + lb) << 3);
        const float* u2p = U2 + n * 4;
        #pragma unroll
        for (int jj = 0; jj < 4; ++jj) d0[jj] = bfbits(u2p[jj]);
        #pragma unroll
        for (int jj = 4; jj < 8; ++jj) d0[jj] = 0;
        short* d1 = Bg + 11 * 4096 + ((nt * 64 + lb + 32) << 3);
        #pragma unroll
        for (int jj = 0; jj < 8; ++jj) d1[jj] = 0;
    }
}

// ---------------------------------------------------------------------------
// Main: 1 node (128 rows x 256 cols) per 512-thread block; 8 waves = 2M x 4N,
// each wave 64 rows x 64 cols -> acc = 4 x v16f (64 regs, spill-free at
// 4 waves/SIMD). B fragments streamed from L2; w3/w2/U1 staged in LDS.
// ---------------------------------------------------------------------------
__global__ __launch_bounds__(512, 4)
void symcon_main(const float* __restrict__ x, const float* __restrict__ y,
                 const float* __restrict__ U1, const float* __restrict__ W3,
                 const float* __restrict__ W2, const float* __restrict__ W1,
                 const short* __restrict__ Bg, float* __restrict__ out)
{
    __shared__ __align__(16) float x_re[128][16];   // 8 KB, permuted x
    __shared__ __align__(16) float w3l[11 * 128];   // 5.5 KB
    __shared__ __align__(16) float w2l[4 * 128];    // 2 KB
    __shared__ __align__(16) float u1l[16];
    __shared__ __align__(16) float Sbuf[128][36];   // 18 KB

    const int tid  = threadIdx.x;
    const int node = blockIdx.x;

    // ---- species (argmax, first-max wins); uniform across block ----
    int e = 0;
    {
        const float* yr = y + node * 10;
        float best = yr[0];
        #pragma unroll
        for (int s2 = 1; s2 < 10; ++s2) { const float v = yr[s2]; if (v > best) { best = v; e = s2; } }
    }

    // ---- stage permuted x tile: x_re[r][(i&1)*8 + (i>>1)] = x[r][i] ----
    {
        const int r = tid >> 2, seg = tid & 3;
        const float4 v = *reinterpret_cast<const float4*>(x + ((size_t)node * 128 + r) * 16 + seg * 4);
        *reinterpret_cast<float2*>(&x_re[r][2 * seg])     = make_float2(v.x, v.z);
        *reinterpret_cast<float2*>(&x_re[r][8 + 2 * seg]) = make_float2(v.y, v.w);
    }
    // ---- stage per-species weights ----
    if (tid < 352) {
        const float4 v = *reinterpret_cast<const float4*>(W3 + e * 1408 + tid * 4);
        *reinterpret_cast<float4*>(&w3l[tid * 4]) = v;
    } else if (tid < 480) {
        const int t = tid - 352;
        const float4 v = *reinterpret_cast<const float4*>(W2 + e * 512 + t * 4);
        *reinterpret_cast<float4*>(&w2l[t * 4]) = v;
    } else if (tid < 496) {
        const int s = tid - 480;                     // slot order
        u1l[s] = U1[2 * (s & 7) + (s >> 3)];
    }

    const int lane = tid & 63;
    const int wid  = tid >> 6;
    const int mw   = wid >> 2;       // 0..1 : which 64-row half
    const int nq   = wid & 3;        // 0..3 : which 64-col quarter
    const int col  = lane & 31;
    const int h    = lane >> 5;
    const int rbA  = mw * 64 + col;  // A-operand channel row (mr=0)

    __syncthreads();

    // x fragments for this wave's two 32-row groups
    float4 xe0, xo0, xe1, xo1;
    {
        xe0 = *reinterpret_cast<const float4*>(&x_re[rbA][4 * h]);
        xo0 = *reinterpret_cast<const float4*>(&x_re[rbA][8 + 4 * h]);
        xe1 = *reinterpret_cast<const float4*>(&x_re[rbA + 32][4 * h]);
        xo1 = *reinterpret_cast<const float4*>(&x_re[rbA + 32][8 + 4 * h]);
    }
    const float xev0[4] = {xe0.x, xe0.y, xe0.z, xe0.w};
    const float xov0[4] = {xo0.x, xo0.y, xo0.z, xo0.w};
    const float xev1[4] = {xe1.x, xe1.y, xe1.z, xe1.w};
    const float xov1[4] = {xo1.x, xo1.y, xo1.z, xo1.w};

    v16f acc[4] = {};   // [mr*2 + ntl]

    // ---- K loop: 11 U3 steps + 1 U2 step; B straight from L2 ----
    const short* Bq = Bg + (nq * 2) * 512 + (lane << 3);
    #pragma unroll
    for (int kt = 0; kt < 12; ++kt) {
        const v8s bf0 = *reinterpret_cast<const v8s*>(Bq + kt * 4096);
        const v8s bf1 = *reinterpret_cast<const v8s*>(Bq + kt * 4096 + 512);
        v8s a0, a1;
        if (kt < 11) {
            const float wa = w3l[kt * 128 + rbA];
            const float wb = w3l[kt * 128 + rbA + 32];
            #pragma unroll
            for (int j2 = 0; j2 < 4; ++j2) {
                a0[2 * j2]     = bfbits(xev0[j2] * wa);
                a0[2 * j2 + 1] = bfbits(xov0[j2] * wa);
                a1[2 * j2]     = bfbits(xev1[j2] * wb);
                a1[2 * j2 + 1] = bfbits(xov1[j2] * wb);
            }
        } else {
            #pragma unroll
            for (int j = 0; j < 8; ++j) { a0[j] = 0; a1[j] = 0; }
            #pragma unroll
            for (int j = 0; j < 4; ++j) {
                const float v0 = w2l[j * 128 + rbA];
                const float v1 = w2l[j * 128 + rbA + 32];
                a0[j] = h ? (short)0 : bfbits(v0);
                a1[j] = h ? (short)0 : bfbits(v1);
            }
        }
        acc[0] = __builtin_amdgcn_mfma_f32_32x32x16_bf16(a0, bf0, acc[0], 0, 0, 0);
        acc[1] = __builtin_amdgcn_mfma_f32_32x32x16_bf16(a0, bf1, acc[1], 0, 0, 0);
        acc[2] = __builtin_amdgcn_mfma_f32_32x32x16_bf16(a1, bf0, acc[2], 0, 0, 0);
        acc[3] = __builtin_amdgcn_mfma_f32_32x32x16_bf16(a1, bf1, acc[3], 0, 0, 0);
    }

    // ---- epilogue: s = (D0*x_p0 + D1*x_p1)*x_q, fold cols via shfl_xor ----
    const int c4    = col >> 4;
    const int q     = col & 15;
    const int qslot = ((q & 1) << 3) | (q >> 1);
    const int xpoff = c4 * 8 + nq * 2;
    #pragma unroll
    for (int mr = 0; mr < 2; ++mr) {
        #pragma unroll
        for (int rg = 0; rg < 16; ++rg) {
            const int row = mw * 64 + mr * 32 + (rg & 3) + ((rg >> 2) << 3) + 4 * h;
            const float  xq = x_re[row][qslot];
            const float2 xp = *reinterpret_cast<const float2*>(&x_re[row][xpoff]);
            float s = (acc[mr * 2][rg] * xp.x + acc[mr * 2 + 1][rg] * xp.y) * xq;
            s += __shfl_xor(s, 16);
            s += __shfl_xor(s, 8);
            if (col < 8) Sbuf[row][nq * 8 + col] = s;
        }
    }

    __syncthreads();   // Sbuf complete

    // ---- final: 4 lanes per row reduce Sbuf(32) + U1 term ----
    {
        const int r = tid >> 2, g = tid & 3;
        const float4 v0 = *reinterpret_cast<const float4*>(&Sbuf[r][g * 8]);
        const float4 v1 = *reinterpret_cast<const float4*>(&Sbuf[r][g * 8 + 4]);
        const float4 xv = *reinterpret_cast<const float4*>(&x_re[r][g * 4]);
        const float4 uv = *reinterpret_cast<const float4*>(&u1l[g * 4]);
        const float w1v = W1[e * 128 + r];
        float s = v0.x + v0.y + v0.z + v0.w + v1.x + v1.y + v1.z + v1.w
                + w1v * (xv.x * uv.x + xv.y * uv.y + xv.z * uv.z + xv.w * uv.w);
        s += __shfl_xor(s, 1);
        s += __shfl_xor(s, 2);
        if (g == 0) out[(size_t)node * 128 + r] = s;
    }
}

extern "C" void kernel_launch(void* const* d_in, const int* in_sizes, int n_in,
                              void* d_out, int out_size, void* d_ws, size_t ws_size,
                              hipStream_t stream) {
    const float* x  = (const float*)d_in[0];
    const float* y  = (const float*)d_in[1];
    const float* U3 = (const float*)d_in[2];
    const float* U2 = (const float*)d_in[3];
    const float* U1 = (const float*)d_in[4];
    const float* W3 = (const float*)d_in[5];
    const float* W2 = (const float*)d_in[6];
    const float* W1 = (const float*)d_in[7];
    short* Bg = (short*)d_ws;   // 96 KB

    symcon_prep<<<16, 256, 0, stream>>>(U3, U2, Bg);
    symcon_main<<<2048, 512, 0, stream>>>(x, y, U1, W3, W2, W1, Bg, (float*)d_out);
}

// Round 6
// 52.344 us; speedup vs baseline: 1.7113x; 1.0273x over previous
//
#include <hip/hip_runtime.h>
#include <hip/hip_bf16.h>

typedef __fp16 h2  __attribute__((ext_vector_type(2)));
typedef __fp16 v8h __attribute__((ext_vector_type(8)));
typedef _Float16 v8f16 __attribute__((ext_vector_type(8)));
typedef float  v16f __attribute__((ext_vector_type(16)));

__device__ __forceinline__ short h16(float f) {
    return __builtin_bit_cast(short, (_Float16)f);   // RNE f32->f16
}

__device__ __forceinline__ void gload16(const short* g, short* l) {
    __builtin_amdgcn_global_load_lds(
        (const __attribute__((address_space(1))) unsigned int*)g,
        (__attribute__((address_space(3))) unsigned int*)l, 16, 0, 0);
}

__device__ __forceinline__ v8h pack4(h2 a, h2 b, h2 c, h2 d) {
    union { int4 i; v8h h; } u;
    u.i = make_int4(__builtin_bit_cast(int, a), __builtin_bit_cast(int, b),
                    __builtin_bit_cast(int, c), __builtin_bit_cast(int, d));
    return u.h;
}

__device__ __forceinline__ v16f mfma_f16(v8h a, v8h b, v16f c) {
    return __builtin_amdgcn_mfma_f32_32x32x16_f16(
        __builtin_bit_cast(v8f16, a), __builtin_bit_cast(v8f16, b), c, 0, 0, 0);
}

// ---------------------------------------------------------------------------
// Prep: U3/U2 -> fragment-ordered fp16 B matrix in global workspace.
// Layout: Bg[kt(12)][nt(8)][lane(64)][j(8)] u16; kt stride 4096.
//   B[k3*16+i, n=p*16+q] = U3[p,q,i,k3]  (lane=(n&31)|((i>>3)<<5), j=i&7)
//   kt=11: B[176+k2, n] = U2[n,k2] at h=0,j=k2<4; rest zero.
// ---------------------------------------------------------------------------
__global__ void symcon_prep(const float* __restrict__ U3, const float* __restrict__ U2,
                            short* __restrict__ Bg)
{
    const int g = blockIdx.x * 256 + threadIdx.x;   // 0..4095
    const int n = g >> 4;                           // output column 0..255
    const int i = g & 15;                           // irrep index 0..15
    const int nt = n >> 5;
    const int lb = n & 31;
    const int lane = lb | ((i >> 3) << 5);
    const int j = i & 7;
    const float* u3p = U3 + n * 176 + i * 11;       // U3[n,i,k3] contiguous in k3
    short* dst = Bg + ((nt * 64 + lane) << 3) + j;
    #pragma unroll
    for (int k3 = 0; k3 < 11; ++k3)
        dst[k3 * 4096] = h16(u3p[k3]);
    if (i == 0) {
        short* d0 = Bg + 11 * 4096 + ((nt * 64 + lb) << 3);
        const float* u2p = U2 + n * 4;
        #pragma unroll
        for (int jj = 0; jj < 4; ++jj) d0[jj] = h16(u2p[jj]);
        #pragma unroll
        for (int jj = 4; jj < 8; ++jj) d0[jj] = 0;
        short* d1 = Bg + 11 * 4096 + ((nt * 64 + lb + 32) << 3);
        #pragma unroll
        for (int jj = 0; jj < 8; ++jj) d1[jj] = 0;
    }
}

// ---------------------------------------------------------------------------
// Main: 1 node (128 rows x 256 cols) per 512-thread block; 8 waves = 2M x 4N.
// fp16 GEMM K=192 (12 kt): B staged global->LDS (dbuf, counted vmcnt, raw
// barriers, sched_barrier-pinned phase regions); A built in-register with
// v_pk_mul_f16. f32 quadratic epilogue.
// Phase map: phase0={kt11(U2), kt0}; phase s>=1={2s-1, 2s}.
// ---------------------------------------------------------------------------
__global__ __launch_bounds__(512, 4)
void symcon_main(const float* __restrict__ x, const float* __restrict__ y,
                 const float* __restrict__ U1, const float* __restrict__ W3,
                 const float* __restrict__ W2, const float* __restrict__ W1,
                 const short* __restrict__ Bg, float* __restrict__ out)
{
    __shared__ __align__(16) short Bl[2][2][4096];  // 32 KB: [buf][sub-kt][nt*lane*j]
    __shared__ __align__(16) float x_re[128][16];   // 8 KB, permuted x
    __shared__ __align__(16) float Sbuf[128][36];   // 18 KB
    __shared__ __align__(16) float u1l[16];

    const int tid  = threadIdx.x;
    const int node = blockIdx.x;
    const int lane = tid & 63;
    const int wid  = tid >> 6;
    const int mw   = wid >> 2;       // 0..1 : 64-row half
    const int nq   = wid & 3;        // 0..3 : 64-col quarter
    const int col  = lane & 31;
    const int h    = lane >> 5;
    const int rbA  = mw * 64 + col;

    // ---- prologue: stage phases 0 and 1 (kts 11,0 and 1,2) ----
    {
        const short* g = Bg + tid * 8;
        gload16(g + 11 * 4096, &Bl[0][0][tid * 8]);
        gload16(g +  0 * 4096, &Bl[0][1][tid * 8]);
        gload16(g +  1 * 4096, &Bl[1][0][tid * 8]);
        gload16(g +  2 * 4096, &Bl[1][1][tid * 8]);
    }

    // ---- species (argmax, first-max wins) ----
    int e = 0;
    {
        const float* yr = y + node * 10;
        float best = yr[0];
        #pragma unroll
        for (int s2 = 1; s2 < 10; ++s2) { const float v = yr[s2]; if (v > best) { best = v; e = s2; } }
    }

    // ---- stage permuted x tile: x_re[r][(i&1)*8 + (i>>1)] = x[r][i] ----
    {
        const int r = tid >> 2, seg = tid & 3;
        const float4 v = *reinterpret_cast<const float4*>(x + ((size_t)node * 128 + r) * 16 + seg * 4);
        *reinterpret_cast<float2*>(&x_re[r][2 * seg])     = make_float2(v.x, v.z);
        *reinterpret_cast<float2*>(&x_re[r][8 + 2 * seg]) = make_float2(v.y, v.w);
    }
    if (tid < 16) u1l[tid] = U1[2 * (tid & 7) + (tid >> 3)];

    // ---- preload per-species weights into registers (coalesced, L2-hot) ----
    float w3a[11], w3b[11], w2a[4], w2b[4];
    #pragma unroll
    for (int k = 0; k < 11; ++k) {
        w3a[k] = W3[(e * 11 + k) * 128 + rbA];
        w3b[k] = W3[(e * 11 + k) * 128 + rbA + 32];
    }
    #pragma unroll
    for (int k = 0; k < 4; ++k) {
        w2a[k] = W2[(e * 4 + k) * 128 + rbA];
        w2b[k] = W2[(e * 4 + k) * 128 + rbA + 32];
    }

    __syncthreads();   // x_re ready; full drain -> phases 0,1 staged, vmcnt=0

    // ---- x as packed half2 (scalar RNE converts, one-time) ----
    h2 xh0[4], xh1[4];
    {
        const float4 e0 = *reinterpret_cast<const float4*>(&x_re[rbA][4 * h]);
        const float4 o0 = *reinterpret_cast<const float4*>(&x_re[rbA][8 + 4 * h]);
        const float4 e1 = *reinterpret_cast<const float4*>(&x_re[rbA + 32][4 * h]);
        const float4 o1 = *reinterpret_cast<const float4*>(&x_re[rbA + 32][8 + 4 * h]);
        xh0[0] = h2{(__fp16)e0.x, (__fp16)o0.x};
        xh0[1] = h2{(__fp16)e0.y, (__fp16)o0.y};
        xh0[2] = h2{(__fp16)e0.z, (__fp16)o0.z};
        xh0[3] = h2{(__fp16)e0.w, (__fp16)o0.w};
        xh1[0] = h2{(__fp16)e1.x, (__fp16)o1.x};
        xh1[1] = h2{(__fp16)e1.y, (__fp16)o1.y};
        xh1[2] = h2{(__fp16)e1.z, (__fp16)o1.z};
        xh1[3] = h2{(__fp16)e1.w, (__fp16)o1.w};
    }

    v16f acc[4] = {};   // [mr*2 + ntl]

    // ---- K loop: 6 phases x 2 kt; dbuf LDS, counted vmcnt, pinned regions ----
    #pragma unroll
    for (int s = 0; s < 6; ++s) {
        if (s == 5) { asm volatile("s_waitcnt vmcnt(0)" ::: "memory"); }
        else        { asm volatile("s_waitcnt vmcnt(2)" ::: "memory"); }
        __builtin_amdgcn_s_barrier();
        __builtin_amdgcn_sched_barrier(0);   // nothing enters/leaves compute region upward

        const short* bb = &Bl[s & 1][0][(nq * 128 + lane) * 8];
        #pragma unroll
        for (int u = 0; u < 2; ++u) {
            const v8h bf0 = *reinterpret_cast<const v8h*>(bb + u * 4096);
            const v8h bf1 = *reinterpret_cast<const v8h*>(bb + u * 4096 + 512);
            v8h a0, a1;
            if (s == 0 && u == 0) {
                // kt=11 (U2): h=0 lanes carry w2 in j=0..3 (scalar RNE converts)
                const h2 z = {};
                const h2 p00 = h ? z : h2{(__fp16)w2a[0], (__fp16)w2a[1]};
                const h2 p01 = h ? z : h2{(__fp16)w2a[2], (__fp16)w2a[3]};
                const h2 p10 = h ? z : h2{(__fp16)w2b[0], (__fp16)w2b[1]};
                const h2 p11 = h ? z : h2{(__fp16)w2b[2], (__fp16)w2b[3]};
                a0 = pack4(p00, p01, z, z);
                a1 = pack4(p10, p11, z, z);
            } else {
                const int kt = (s == 0) ? 0 : (2 * s - 1 + u);
                const __fp16 wha = (__fp16)w3a[kt];
                const __fp16 whb = (__fp16)w3b[kt];
                const h2 wa = h2{wha, wha};
                const h2 wb = h2{whb, whb};
                a0 = pack4(xh0[0] * wa, xh0[1] * wa, xh0[2] * wa, xh0[3] * wa);
                a1 = pack4(xh1[0] * wb, xh1[1] * wb, xh1[2] * wb, xh1[3] * wb);
            }
            acc[0] = mfma_f16(a0, bf0, acc[0]);
            acc[1] = mfma_f16(a0, bf1, acc[1]);
            acc[2] = mfma_f16(a1, bf0, acc[2]);
            acc[3] = mfma_f16(a1, bf1, acc[3]);
        }

        __builtin_amdgcn_sched_barrier(0);   // ds_reads/MFMAs may not sink past here
        __builtin_amdgcn_s_barrier();        // all waves consumed buf[s&1]
        if (s < 4) {                         // stage phase s+2 = {2s+3, 2s+4} into buf[s&1]
            const short* g = Bg + tid * 8;
            gload16(g + (2 * s + 3) * 4096, &Bl[s & 1][0][tid * 8]);
            gload16(g + (2 * s + 4) * 4096, &Bl[s & 1][1][tid * 8]);
        }
    }

    // ---- epilogue: s = (D0*x_p0 + D1*x_p1)*x_q, fold cols via shfl_xor ----
    const int c4    = col >> 4;
    const int q     = col & 15;
    const int qslot = ((q & 1) << 3) | (q >> 1);
    const int xpoff = c4 * 8 + nq * 2;
    #pragma unroll
    for (int mr = 0; mr < 2; ++mr) {
        #pragma unroll
        for (int rg = 0; rg < 16; ++rg) {
            const int row = mw * 64 + mr * 32 + (rg & 3) + ((rg >> 2) << 3) + 4 * h;
            const float  xq = x_re[row][qslot];
            const float2 xp = *reinterpret_cast<const float2*>(&x_re[row][xpoff]);
            float s = (acc[mr * 2][rg] * xp.x + acc[mr * 2 + 1][rg] * xp.y) * xq;
            s += __shfl_xor(s, 16);
            s += __shfl_xor(s, 8);
            if (col < 8) Sbuf[row][nq * 8 + col] = s;
        }
    }

    __syncthreads();   // Sbuf complete

    // ---- final: 4 lanes per row reduce Sbuf(32) + U1 term ----
    {
        const int r = tid >> 2, g = tid & 3;
        const float4 v0 = *reinterpret_cast<const float4*>(&Sbuf[r][g * 8]);
        const float4 v1 = *reinterpret_cast<const float4*>(&Sbuf[r][g * 8 + 4]);
        const float4 xv = *reinterpret_cast<const float4*>(&x_re[r][g * 4]);
        const float4 uv = *reinterpret_cast<const float4*>(&u1l[g * 4]);
        const float w1v = W1[e * 128 + r];
        float s = v0.x + v0.y + v0.z + v0.w + v1.x + v1.y + v1.z + v1.w
                + w1v * (xv.x * uv.x + xv.y * uv.y + xv.z * uv.z + xv.w * uv.w);
        s += __shfl_xor(s, 1);
        s += __shfl_xor(s, 2);
        if (g == 0) out[(size_t)node * 128 + r] = s;
    }
}

extern "C" void kernel_launch(void* const* d_in, const int* in_sizes, int n_in,
                              void* d_out, int out_size, void* d_ws, size_t ws_size,
                              hipStream_t stream) {
    const float* x  = (const float*)d_in[0];
    const float* y  = (const float*)d_in[1];
    const float* U3 = (const float*)d_in[2];
    const float* U2 = (const float*)d_in[3];
    const float* U1 = (const float*)d_in[4];
    const float* W3 = (const float*)d_in[5];
    const float* W2 = (const float*)d_in[6];
    const float* W1 = (const float*)d_in[7];
    short* Bg = (short*)d_ws;   // 96 KB fp16 B matrix

    symcon_prep<<<16, 256, 0, stream>>>(U3, U2, Bg);
    symcon_main<<<2048, 512, 0, stream>>>(x, y, U1, W3, W2, W1, Bg, (float*)d_out);
}